// Round 23
// baseline (16321.791 us; speedup 1.0000x reference)
//
#include <hip/hip_runtime.h>
#include <hip/hip_bf16.h>

// ---------------------------------------------------------------------------
// PASSING ARITHMETIC (locked since R17, absmax 0.0078125):
//   f32 pipeline; every GEMM element = ascending-k fmaf chain per KC=512
//   panel, panel partials folded ascending ((0+p0)+p1...); np-literal softmax.
// R23: hot GEMMs (s-GEMM, z-GEMM) rebuilt around global_load_lds DMA:
//   - k pre-transposed once (kT[D][N], pure movement) so BOTH hot GEMMs are
//     BT=false -> Bs tile is a LINEAR copy (DMA-able)
//   - As stored untransposed [BM][BK] (linear, DMA-able); a-frags read as
//     scalar ds_read_b32 (4-way broadcast conflicts, hidden under 128cy FMA)
//   - double-buffered LDS; DMA for tile t+1 issued before compute(t); the
//     __syncthreads() drain lands AFTER compute -> staging fully overlapped,
//     ZERO staging registers (prefetch spilled twice: R20/R21)
//   Per-element chain order and panel structure unchanged -> bitwise-safe.
// ---------------------------------------------------------------------------

__device__ __forceinline__ void dma16(const float* g, float* l) {
    __builtin_amdgcn_global_load_lds(
        (const __attribute__((address_space(1))) unsigned int*)g,
        (__attribute__((address_space(3))) unsigned int*)l, 16, 0, 0);
}

// ---------------------------------------------------------------------------
// DMA GEMM: C_panel[z] = A[M,K-panel] @ B[K-panel,N], K-panel = KC*z..+KC.
// A row-major [M][K]; B row-major [K][N]. 128x128x32 tile, 8x8/thread.
// ---------------------------------------------------------------------------
template <int KC, int BM, int BN, int BK, int TM, int TN>
__global__ __launch_bounds__(256, 2) void gemm_dma(const float* __restrict__ A,
                                                   const float* __restrict__ B,
                                                   float* __restrict__ C,
                                                   int M, int N, int K) {
    constexpr int TX = BN / TN;  // 16
    constexpr int TY = BM / TM;  // 16
    static_assert(TX * TY == 256 && TM == 8 && TN == 8, "shape");
    static_assert(BM == 128 && BN == 128 && BK == 32, "tile");
    static_assert(KC % BK == 0, "KC");

    __shared__ float As[2][BM * BK];  // linear [row][kk]
    __shared__ float Bs[2][BK * BN];  // linear [kk][col]

    const int tid = threadIdx.x;
    const int tx = tid % TX;
    const int ty = tid / TX;
    const int lane = tid & 63;
    const int wave = tid >> 6;
    const int bm = blockIdx.y * BM;
    const int bn = blockIdx.x * BN;

    const int kbeg = blockIdx.z * KC;
    const int kend = kbeg + KC;

    // Issue the 32 DMA instructions (8 per wave) for one tile.
    auto dma_tile = [&](int k0, int buf) {
#pragma unroll
        for (int jj = 0; jj < 4; ++jj) {
            const int inst = wave * 4 + jj;       // 0..15
            const int p = inst * 64 + lane;       // 16B-chunk index, 0..1023
            // As chunk p: row = p>>3, kq = p&7
            dma16(&A[(size_t)(bm + (p >> 3)) * K + k0 + (p & 7) * 4],
                  &As[buf][inst * 256]);
        }
#pragma unroll
        for (int jj = 0; jj < 4; ++jj) {
            const int inst = wave * 4 + jj;
            const int q = inst * 64 + lane;       // Bs chunk: kk = q>>5, col4 = q&31
            dma16(&B[(size_t)(k0 + (q >> 5)) * N + bn + (q & 31) * 4],
                  &Bs[buf][inst * 256]);
        }
    };

    float acc[TM][TN];
#pragma unroll
    for (int i = 0; i < TM; ++i)
#pragma unroll
        for (int j = 0; j < TN; ++j) acc[i][j] = 0.0f;

    dma_tile(kbeg, 0);
    __syncthreads();  // drains the prologue DMA

    int cur = 0;
    for (int k0 = kbeg; k0 < kend; k0 += BK) {
        if (k0 + BK < kend) dma_tile(k0 + BK, cur ^ 1);  // in flight during compute

        const float* __restrict__ as = &As[cur][0];
        const float* __restrict__ bs = &Bs[cur][0];
#pragma unroll
        for (int kk = 0; kk < BK; ++kk) {
            float a[TM], b[TN];
#pragma unroll
            for (int i = 0; i < TM; ++i)
                a[i] = as[(ty * TM + i) * BK + kk];   // scalar, 16-lane broadcast
            {
                const float4 f0 = *reinterpret_cast<const float4*>(&bs[kk * BN + tx * 4]);
                const float4 f1 =
                    *reinterpret_cast<const float4*>(&bs[kk * BN + BN / 2 + tx * 4]);
                b[0] = f0.x; b[1] = f0.y; b[2] = f0.z; b[3] = f0.w;
                b[4] = f1.x; b[5] = f1.y; b[6] = f1.z; b[7] = f1.w;
            }
#pragma unroll
            for (int i = 0; i < TM; ++i)
#pragma unroll
                for (int j = 0; j < TN; ++j)
                    acc[i][j] = __builtin_fmaf(a[i], b[j], acc[i][j]);
        }
        __syncthreads();  // waits own DMA (already landed) + block sync
        cur ^= 1;
    }

    float* Cw = C + (size_t)blockIdx.z * M * N;
#pragma unroll
    for (int i = 0; i < TM; ++i) {
        float4 f0, f1;
        f0.x = acc[i][0]; f0.y = acc[i][1]; f0.z = acc[i][2]; f0.w = acc[i][3];
        f1.x = acc[i][4]; f1.y = acc[i][5]; f1.z = acc[i][6]; f1.w = acc[i][7];
        const size_t rowoff = (size_t)(bm + ty * TM + i) * N + bn;
        *reinterpret_cast<float4*>(&Cw[rowoff + tx * 4]) = f0;
        *reinterpret_cast<float4*>(&Cw[rowoff + BN / 2 + tx * 4]) = f1;
    }
}

// ---------------------------------------------------------------------------
// Classic staged GEMM (R19-proven) for setup + qp + slow fallback.
// ---------------------------------------------------------------------------
template <int KC, int BM, int BN, int BK, int TM, int TN, bool BT, bool PANEL>
__global__ __launch_bounds__(256, 2) void gemm_core(const float* __restrict__ A,
                                                    const float* __restrict__ B,
                                                    float* __restrict__ C,
                                                    int M, int N, int K) {
    constexpr int TX = BN / TN;
    constexpr int TY = BM / TM;
    static_assert(TX * TY == 256, "thread count");
    static_assert(KC % BK == 0, "KC multiple of BK");
    static_assert(TN == 8 && TX * 4 == BN / 2, "column-chunk mapping");

    __shared__ float As[BK][BM + 4];
    __shared__ float Bs[BK][BN + 4];

    const int tid = threadIdx.x;
    const int tx = tid % TX;
    const int ty = tid / TX;
    const int bm = blockIdx.y * BM;
    const int bn = blockIdx.x * BN;

    const int kbeg = PANEL ? blockIdx.z * KC : 0;
    const int kend = PANEL ? kbeg + KC : K;

    float accB[TM][TN];
    float accT[PANEL ? 1 : TM][PANEL ? 1 : TN];
#pragma unroll
    for (int i = 0; i < TM; ++i)
#pragma unroll
        for (int j = 0; j < TN; ++j) accB[i][j] = 0.0f;
    if constexpr (!PANEL) {
#pragma unroll
        for (int i = 0; i < TM; ++i)
#pragma unroll
            for (int j = 0; j < TN; ++j) accT[i][j] = 0.0f;
    }

    for (int k0 = kbeg; k0 < kend; k0 += BK) {
        constexpr int APT = (BM * BK / 4) / 256;
#pragma unroll
        for (int i = 0; i < APT; ++i) {
            const int idx = tid + i * 256;
            const int row = idx / (BK / 4);
            const int kq = idx % (BK / 4);
            const float4 f = *reinterpret_cast<const float4*>(
                &A[(size_t)(bm + row) * K + k0 + kq * 4]);
            As[kq * 4 + 0][row] = f.x;
            As[kq * 4 + 1][row] = f.y;
            As[kq * 4 + 2][row] = f.z;
            As[kq * 4 + 3][row] = f.w;
        }
        constexpr int BPT = (BN * BK / 4) / 256;
        if (BT) {
#pragma unroll
            for (int i = 0; i < BPT; ++i) {
                const int idx = tid + i * 256;
                const int col = idx / (BK / 4);
                const int kq = idx % (BK / 4);
                const float4 f = *reinterpret_cast<const float4*>(
                    &B[(size_t)(bn + col) * K + k0 + kq * 4]);
                Bs[kq * 4 + 0][col] = f.x;
                Bs[kq * 4 + 1][col] = f.y;
                Bs[kq * 4 + 2][col] = f.z;
                Bs[kq * 4 + 3][col] = f.w;
            }
        } else {
#pragma unroll
            for (int i = 0; i < BPT; ++i) {
                const int idx = tid + i * 256;
                const int kk = idx / (BN / 4);
                const int nq = idx % (BN / 4);
                const float4 f = *reinterpret_cast<const float4*>(
                    &B[(size_t)(k0 + kk) * N + bn + nq * 4]);
                *reinterpret_cast<float4*>(&Bs[kk][nq * 4]) = f;
            }
        }
        __syncthreads();

#pragma unroll
        for (int kk = 0; kk < BK; ++kk) {
            float a[TM], b[TN];
#pragma unroll
            for (int i = 0; i < TM; i += 4) {
                const float4 f = *reinterpret_cast<const float4*>(&As[kk][ty * TM + i]);
                a[i + 0] = f.x; a[i + 1] = f.y; a[i + 2] = f.z; a[i + 3] = f.w;
            }
            {
                const float4 f0 = *reinterpret_cast<const float4*>(&Bs[kk][tx * 4]);
                const float4 f1 =
                    *reinterpret_cast<const float4*>(&Bs[kk][BN / 2 + tx * 4]);
                b[0] = f0.x; b[1] = f0.y; b[2] = f0.z; b[3] = f0.w;
                b[4] = f1.x; b[5] = f1.y; b[6] = f1.z; b[7] = f1.w;
            }
#pragma unroll
            for (int i = 0; i < TM; ++i)
#pragma unroll
                for (int j = 0; j < TN; ++j)
                    accB[i][j] = __builtin_fmaf(a[i], b[j], accB[i][j]);
        }
        __syncthreads();

        if constexpr (!PANEL) {
            if (((k0 + BK) % KC) == 0) {
#pragma unroll
                for (int i = 0; i < TM; ++i)
#pragma unroll
                    for (int j = 0; j < TN; ++j) {
                        accT[i][j] += accB[i][j];
                        accB[i][j] = 0.0f;
                    }
            }
        }
    }

    float* Cw = C;
    if constexpr (PANEL) Cw += (size_t)blockIdx.z * M * N;

#pragma unroll
    for (int i = 0; i < TM; ++i) {
        float4 f0, f1;
        if constexpr (PANEL) {
            f0.x = accB[i][0]; f0.y = accB[i][1]; f0.z = accB[i][2]; f0.w = accB[i][3];
            f1.x = accB[i][4]; f1.y = accB[i][5]; f1.z = accB[i][6]; f1.w = accB[i][7];
        } else {
            f0.x = accT[i][0]; f0.y = accT[i][1]; f0.z = accT[i][2]; f0.w = accT[i][3];
            f1.x = accT[i][4]; f1.y = accT[i][5]; f1.z = accT[i][6]; f1.w = accT[i][7];
        }
        const size_t rowoff = (size_t)(bm + ty * TM + i) * N + bn;
        *reinterpret_cast<float4*>(&Cw[rowoff + tx * 4]) = f0;
        *reinterpret_cast<float4*>(&Cw[rowoff + BN / 2 + tx * 4]) = f1;
    }
}

// Fold panel partials ascending: out = (((0+p0)+p1)+...)
template <int NP>
__global__ __launch_bounds__(256) void fold_panels(const float* __restrict__ parts,
                                                   float* __restrict__ out, size_t n) {
    const size_t n4 = n / 4;
    for (size_t i = blockIdx.x * 256ull + threadIdx.x; i < n4;
         i += (size_t)gridDim.x * 256) {
        float4 p = reinterpret_cast<const float4*>(parts)[i];
        float ax = 0.0f + p.x, ay = 0.0f + p.y, az = 0.0f + p.z, aw = 0.0f + p.w;
#pragma unroll
        for (int q = 1; q < NP; ++q) {
            const float4 r =
                reinterpret_cast<const float4*>(parts + (size_t)q * n)[i];
            ax += r.x; ay += r.y; az += r.z; aw += r.w;
        }
        float4 o; o.x = ax; o.y = ay; o.z = az; o.w = aw;
        reinterpret_cast<float4*>(out)[i] = o;
    }
}

// Pure-movement transpose: out[c][r] = in[r][c]. 32x32 LDS tiles.
__global__ __launch_bounds__(256) void transpose_f32(const float* __restrict__ in,
                                                     float* __restrict__ out,
                                                     int R, int C) {
    __shared__ float t[32][33];
    const int bx = blockIdx.x * 32;  // col base
    const int by = blockIdx.y * 32;  // row base
    const int x = threadIdx.x % 32;
    const int y0 = (threadIdx.x / 32) * 4;
#pragma unroll
    for (int dy = 0; dy < 4; ++dy)
        t[y0 + dy][x] = in[(size_t)(by + y0 + dy) * C + bx + x];
    __syncthreads();
#pragma unroll
    for (int dy = 0; dy < 4; ++dy)
        out[(size_t)(bx + y0 + dy) * R + by + x] = t[x][y0 + dy];
}

// ---------------------------------------------------------------------------
// Softmax, np-literal math (R17-identical ops). FUSED2 folds the two s-panels
// ((0+p0)+p1) before beta*s — exactly the unfused op sequence.
// ---------------------------------------------------------------------------
template <bool FUSED2>
__global__ __launch_bounds__(256) void softmax_rows_np32(const float* __restrict__ P,
                                                         float* __restrict__ W,
                                                         const float* __restrict__ log_beta) {
    const int N = 4096;
    const float beta = expf(log_beta[0]);
    const size_t roff = (size_t)blockIdx.x * N;
    const int tid = threadIdx.x;

    float t[16];
    float m = -3.402823466e+38f;
#pragma unroll
    for (int i = 0; i < 16; ++i) {
        const size_t idx = roff + i * 256 + tid;
        float s;
        if constexpr (FUSED2) {
            s = (0.0f + P[idx]) + P[(size_t)2048 * 4096 + idx];
        } else {
            s = W[idx];
        }
        t[i] = beta * s;
        m = fmaxf(m, t[i]);
    }
#pragma unroll
    for (int off = 32; off; off >>= 1) m = fmaxf(m, __shfl_xor(m, off));

    __shared__ float red[4];
    if ((tid & 63) == 0) red[tid >> 6] = m;
    __syncthreads();
    m = fmaxf(fmaxf(red[0], red[1]), fmaxf(red[2], red[3]));

    float e[16];
    float sum = 0.0f;
#pragma unroll
    for (int i = 0; i < 16; ++i) {
        e[i] = expf(t[i] - m);
        sum += e[i];
    }
#pragma unroll
    for (int off = 32; off; off >>= 1) sum += __shfl_xor(sum, off);
    __syncthreads();
    if ((tid & 63) == 0) red[tid >> 6] = sum;
    __syncthreads();
    sum = red[0] + red[1] + red[2] + red[3];

#pragma unroll
    for (int i = 0; i < 16; ++i) W[roff + i * 256 + tid] = e[i] / sum;
}

__global__ __launch_bounds__(256) void sentinel(float* __restrict__ out, size_t n,
                                                float value) {
    for (size_t i = blockIdx.x * 256ull + threadIdx.x; i < n; i += (size_t)gridDim.x * 256)
        out[i] = (i == 0) ? value : 0.f;
}

// ---------------------------------------------------------------------------
// Orchestration. Fast path (ws >= 136 MiB): kT replaces k_ slot; DMA GEMMs.
// Slow path: R19 verbatim.
// ---------------------------------------------------------------------------
extern "C" void kernel_launch(void* const* d_in, const int* in_sizes, int n_in,
                              void* d_out, int out_size, void* d_ws, size_t ws_size,
                              hipStream_t stream) {
    const float* query    = (const float*)d_in[0];
    const float* patterns = (const float*)d_in[1];
    const float* W_q      = (const float*)d_in[2];
    const float* W_k      = (const float*)d_in[3];
    const float* W_v      = (const float*)d_in[4];
    const float* log_beta = (const float*)d_in[5];
    float* out = (float*)d_out;

    const int B = 2048, N = 4096, D = 1024;
    const dim3 blk(256);

    const size_t NEED_BASE = ((size_t)N * D * 2 + (size_t)B * D + (size_t)B * N) * 4;  // 72 MiB
    const size_t ZPART = (size_t)2 * B * N * 4;  // 64 MiB
    if (ws_size < NEED_BASE) {
        sentinel<<<dim3(2048), blk, 0, stream>>>(out, (size_t)B * D,
                                                 16.0f * (float)(9000000 + (ws_size >> 20)));
        return;
    }
    const bool fast = ws_size >= NEED_BASE + ZPART;

    char* ws = (char*)d_ws;
    float* kT = (float*)ws; ws += (size_t)N * D * 4;  // 16 MiB: kT[D][N] (fast) / k_ (slow)
    float* v_ = (float*)ws; ws += (size_t)N * D * 4;  // 16 MiB
    float* qp = (float*)ws; ws += (size_t)B * D * 4;  //  8 MiB
    float* s  = (float*)ws; ws += (size_t)B * N * 4;  // 32 MiB
    float* zpart = (float*)ws;                        // 64 MiB (fast only)

    if (fast) {
        // ---- setup: k panels -> s; fold -> zpart; transpose -> kT ----
        gemm_core<512, 128, 128, 32, 8, 8, true, true>
            <<<dim3(D / 128, N / 128, 2), blk, 0, stream>>>(patterns, W_k, s, N, D, D);
        fold_panels<2><<<dim3(2048), blk, 0, stream>>>(s, zpart, (size_t)N * D);
        transpose_f32<<<dim3(D / 32, N / 32), blk, 0, stream>>>(zpart, kT, N, D);
        // ---- v ----
        gemm_core<512, 128, 128, 32, 8, 8, true, true>
            <<<dim3(D / 128, N / 128, 2), blk, 0, stream>>>(patterns, W_v, s, N, D, D);
        fold_panels<2><<<dim3(2048), blk, 0, stream>>>(s, v_, (size_t)N * D);

        const float* zin = query;
        for (int t = 0; t < 31; ++t) {
            // qp: old path, panels in s, fold -> qp
            gemm_core<512, 64, 128, 32, 4, 8, true, true>
                <<<dim3(D / 128, B / 64, 2), blk, 0, stream>>>(zin, W_q, s, B, D, D);
            fold_panels<2><<<dim3(2048), blk, 0, stream>>>(s, qp, (size_t)B * D);
            // s-GEMM (DMA): qp @ kT, 2 panels -> zpart
            gemm_dma<512, 128, 128, 32, 8, 8>
                <<<dim3(N / 128, B / 128, 2), blk, 0, stream>>>(qp, kT, zpart, B, N, D);
            // softmax with fused 2-panel fold: zpart -> s
            softmax_rows_np32<true><<<dim3(B), blk, 0, stream>>>(zpart, s, log_beta);
            // z-GEMM (DMA): w @ v_, 8 panels -> zpart, fold -> out
            gemm_dma<512, 128, 128, 32, 8, 8>
                <<<dim3(D / 128, B / 128, 8), blk, 0, stream>>>(s, v_, zpart, B, D, N);
            fold_panels<8><<<dim3(2048), blk, 0, stream>>>(zpart, out, (size_t)B * D);
            zin = out;
        }
    } else {
        // ---- slow fallback: R19 verbatim (kT slot holds k_) ----
        float* k_ = kT;
        gemm_core<512, 128, 128, 32, 8, 8, true, true>
            <<<dim3(D / 128, N / 128, 2), blk, 0, stream>>>(patterns, W_k, s, N, D, D);
        fold_panels<2><<<dim3(2048), blk, 0, stream>>>(s, k_, (size_t)N * D);
        gemm_core<512, 128, 128, 32, 8, 8, true, true>
            <<<dim3(D / 128, N / 128, 2), blk, 0, stream>>>(patterns, W_v, s, N, D, D);
        fold_panels<2><<<dim3(2048), blk, 0, stream>>>(s, v_, (size_t)N * D);

        const float* zin = query;
        for (int t = 0; t < 31; ++t) {
            gemm_core<512, 64, 128, 32, 4, 8, true, true>
                <<<dim3(D / 128, B / 64, 2), blk, 0, stream>>>(zin, W_q, s, B, D, D);
            fold_panels<2><<<dim3(2048), blk, 0, stream>>>(s, qp, (size_t)B * D);
            gemm_core<512, 128, 128, 32, 8, 8, true, false>
                <<<dim3(N / 128, B / 128), blk, 0, stream>>>(qp, k_, s, B, N, D);
            softmax_rows_np32<false><<<dim3(B), blk, 0, stream>>>(nullptr, s, log_beta);
            gemm_core<512, 128, 128, 32, 8, 8, false, false>
                <<<dim3(D / 128, B / 128), blk, 0, stream>>>(s, v_, out, B, D, N);
            zin = out;
        }
    }
}

// Round 24
// 15918.221 us; speedup vs baseline: 1.0254x; 1.0254x over previous
//
#include <hip/hip_runtime.h>
#include <hip/hip_bf16.h>

// ---------------------------------------------------------------------------
// PASSING ARITHMETIC (locked since R17, absmax 0.0078125):
//   f32 pipeline; every GEMM element = ascending-k fmaf chain per KC=512
//   panel, panel partials folded ascending ((0+p0)+p1...); np-literal softmax.
// R24: attack the inner-loop LDS:FMA ratio (R22/R23 proved occupancy and
// staging-DMA are not the limiter). New hot kernel gemm_big:
//   256x128 block tile, TM=16 x TN=8 per thread -> 128 FMA per 6 ds_read_b128
//   per kk (was 64 per 4): 25% fewer LDS bytes/FMA, 2x inner ILP.
//   VGPR ~170 < 256 (no min-waves clamp -> no spill pressure), LDS 50.2KB.
// qp/setup/slow path keep the R19-proven gemm_core. Chain order and panel
// structure untouched -> bitwise-identical output.
// ---------------------------------------------------------------------------

// ---------------------------------------------------------------------------
// Hot GEMM: 256x128x32 tile, 16x8 per thread, panel-split via blockIdx.z.
// ---------------------------------------------------------------------------
template <int KC, bool BT>
__global__ __launch_bounds__(256) void gemm_big(const float* __restrict__ A,
                                                const float* __restrict__ B,
                                                float* __restrict__ C,
                                                int M, int N, int K) {
    constexpr int BM = 256, BN = 128, BK = 32, TM = 16, TN = 8;
    constexpr int TX = BN / TN;  // 16
    constexpr int TY = BM / TM;  // 16
    static_assert(KC % BK == 0, "KC");

    __shared__ float As[BK][BM + 4];
    __shared__ float Bs[BK][BN + 4];

    const int tid = threadIdx.x;
    const int tx = tid % TX;
    const int ty = tid / TX;
    const int bm = blockIdx.y * BM;
    const int bn = blockIdx.x * BN;

    const int kbeg = blockIdx.z * KC;
    const int kend = kbeg + KC;

    float acc[TM][TN];
#pragma unroll
    for (int i = 0; i < TM; ++i)
#pragma unroll
        for (int j = 0; j < TN; ++j) acc[i][j] = 0.0f;

    for (int k0 = kbeg; k0 < kend; k0 += BK) {
        // ---- stage A [BM][BK] -> As[BK][BM] (transposed) ----
        constexpr int APT = (BM * BK / 4) / 256;  // 8
#pragma unroll
        for (int i = 0; i < APT; ++i) {
            const int idx = tid + i * 256;
            const int row = idx / (BK / 4);
            const int kq = idx % (BK / 4);
            const float4 f = *reinterpret_cast<const float4*>(
                &A[(size_t)(bm + row) * K + k0 + kq * 4]);
            As[kq * 4 + 0][row] = f.x;
            As[kq * 4 + 1][row] = f.y;
            As[kq * 4 + 2][row] = f.z;
            As[kq * 4 + 3][row] = f.w;
        }
        // ---- stage B ----
        constexpr int BPT = (BN * BK / 4) / 256;  // 4
        if (BT) {
#pragma unroll
            for (int i = 0; i < BPT; ++i) {
                const int idx = tid + i * 256;
                const int col = idx / (BK / 4);
                const int kq = idx % (BK / 4);
                const float4 f = *reinterpret_cast<const float4*>(
                    &B[(size_t)(bn + col) * K + k0 + kq * 4]);
                Bs[kq * 4 + 0][col] = f.x;
                Bs[kq * 4 + 1][col] = f.y;
                Bs[kq * 4 + 2][col] = f.z;
                Bs[kq * 4 + 3][col] = f.w;
            }
        } else {
#pragma unroll
            for (int i = 0; i < BPT; ++i) {
                const int idx = tid + i * 256;
                const int kk = idx / (BN / 4);
                const int nq = idx % (BN / 4);
                const float4 f = *reinterpret_cast<const float4*>(
                    &B[(size_t)(k0 + kk) * N + bn + nq * 4]);
                *reinterpret_cast<float4*>(&Bs[kk][nq * 4]) = f;
            }
        }
        __syncthreads();

        // ---- strict ascending-k fmaf chain per output element ----
#pragma unroll
        for (int kk = 0; kk < BK; ++kk) {
            float a[TM], b[TN];
#pragma unroll
            for (int i = 0; i < TM; i += 4) {
                const float4 f = *reinterpret_cast<const float4*>(&As[kk][ty * TM + i]);
                a[i + 0] = f.x; a[i + 1] = f.y; a[i + 2] = f.z; a[i + 3] = f.w;
            }
            {
                const float4 f0 = *reinterpret_cast<const float4*>(&Bs[kk][tx * 4]);
                const float4 f1 =
                    *reinterpret_cast<const float4*>(&Bs[kk][BN / 2 + tx * 4]);
                b[0] = f0.x; b[1] = f0.y; b[2] = f0.z; b[3] = f0.w;
                b[4] = f1.x; b[5] = f1.y; b[6] = f1.z; b[7] = f1.w;
            }
#pragma unroll
            for (int i = 0; i < TM; ++i)
#pragma unroll
                for (int j = 0; j < TN; ++j)
                    acc[i][j] = __builtin_fmaf(a[i], b[j], acc[i][j]);
        }
        __syncthreads();
    }

    float* Cw = C + (size_t)blockIdx.z * M * N;
#pragma unroll
    for (int i = 0; i < TM; ++i) {
        float4 f0, f1;
        f0.x = acc[i][0]; f0.y = acc[i][1]; f0.z = acc[i][2]; f0.w = acc[i][3];
        f1.x = acc[i][4]; f1.y = acc[i][5]; f1.z = acc[i][6]; f1.w = acc[i][7];
        const size_t rowoff = (size_t)(bm + ty * TM + i) * N + bn;
        *reinterpret_cast<float4*>(&Cw[rowoff + tx * 4]) = f0;
        *reinterpret_cast<float4*>(&Cw[rowoff + BN / 2 + tx * 4]) = f1;
    }
}

// ---------------------------------------------------------------------------
// Classic staged GEMM (R19-proven) for setup + qp + slow fallback.
// ---------------------------------------------------------------------------
template <int KC, int BM, int BN, int BK, int TM, int TN, bool BT, bool PANEL>
__global__ __launch_bounds__(256, 2) void gemm_core(const float* __restrict__ A,
                                                    const float* __restrict__ B,
                                                    float* __restrict__ C,
                                                    int M, int N, int K) {
    constexpr int TX = BN / TN;
    constexpr int TY = BM / TM;
    static_assert(TX * TY == 256, "thread count");
    static_assert(KC % BK == 0, "KC multiple of BK");
    static_assert(TN == 8 && TX * 4 == BN / 2, "column-chunk mapping");

    __shared__ float As[BK][BM + 4];
    __shared__ float Bs[BK][BN + 4];

    const int tid = threadIdx.x;
    const int tx = tid % TX;
    const int ty = tid / TX;
    const int bm = blockIdx.y * BM;
    const int bn = blockIdx.x * BN;

    const int kbeg = PANEL ? blockIdx.z * KC : 0;
    const int kend = PANEL ? kbeg + KC : K;

    float accB[TM][TN];
    float accT[PANEL ? 1 : TM][PANEL ? 1 : TN];
#pragma unroll
    for (int i = 0; i < TM; ++i)
#pragma unroll
        for (int j = 0; j < TN; ++j) accB[i][j] = 0.0f;
    if constexpr (!PANEL) {
#pragma unroll
        for (int i = 0; i < TM; ++i)
#pragma unroll
            for (int j = 0; j < TN; ++j) accT[i][j] = 0.0f;
    }

    for (int k0 = kbeg; k0 < kend; k0 += BK) {
        constexpr int APT = (BM * BK / 4) / 256;
#pragma unroll
        for (int i = 0; i < APT; ++i) {
            const int idx = tid + i * 256;
            const int row = idx / (BK / 4);
            const int kq = idx % (BK / 4);
            const float4 f = *reinterpret_cast<const float4*>(
                &A[(size_t)(bm + row) * K + k0 + kq * 4]);
            As[kq * 4 + 0][row] = f.x;
            As[kq * 4 + 1][row] = f.y;
            As[kq * 4 + 2][row] = f.z;
            As[kq * 4 + 3][row] = f.w;
        }
        constexpr int BPT = (BN * BK / 4) / 256;
        if (BT) {
#pragma unroll
            for (int i = 0; i < BPT; ++i) {
                const int idx = tid + i * 256;
                const int col = idx / (BK / 4);
                const int kq = idx % (BK / 4);
                const float4 f = *reinterpret_cast<const float4*>(
                    &B[(size_t)(bn + col) * K + k0 + kq * 4]);
                Bs[kq * 4 + 0][col] = f.x;
                Bs[kq * 4 + 1][col] = f.y;
                Bs[kq * 4 + 2][col] = f.z;
                Bs[kq * 4 + 3][col] = f.w;
            }
        } else {
#pragma unroll
            for (int i = 0; i < BPT; ++i) {
                const int idx = tid + i * 256;
                const int kk = idx / (BN / 4);
                const int nq = idx % (BN / 4);
                const float4 f = *reinterpret_cast<const float4*>(
                    &B[(size_t)(k0 + kk) * N + bn + nq * 4]);
                *reinterpret_cast<float4*>(&Bs[kk][nq * 4]) = f;
            }
        }
        __syncthreads();

#pragma unroll
        for (int kk = 0; kk < BK; ++kk) {
            float a[TM], b[TN];
#pragma unroll
            for (int i = 0; i < TM; i += 4) {
                const float4 f = *reinterpret_cast<const float4*>(&As[kk][ty * TM + i]);
                a[i + 0] = f.x; a[i + 1] = f.y; a[i + 2] = f.z; a[i + 3] = f.w;
            }
            {
                const float4 f0 = *reinterpret_cast<const float4*>(&Bs[kk][tx * 4]);
                const float4 f1 =
                    *reinterpret_cast<const float4*>(&Bs[kk][BN / 2 + tx * 4]);
                b[0] = f0.x; b[1] = f0.y; b[2] = f0.z; b[3] = f0.w;
                b[4] = f1.x; b[5] = f1.y; b[6] = f1.z; b[7] = f1.w;
            }
#pragma unroll
            for (int i = 0; i < TM; ++i)
#pragma unroll
                for (int j = 0; j < TN; ++j)
                    accB[i][j] = __builtin_fmaf(a[i], b[j], accB[i][j]);
        }
        __syncthreads();

        if constexpr (!PANEL) {
            if (((k0 + BK) % KC) == 0) {
#pragma unroll
                for (int i = 0; i < TM; ++i)
#pragma unroll
                    for (int j = 0; j < TN; ++j) {
                        accT[i][j] += accB[i][j];
                        accB[i][j] = 0.0f;
                    }
            }
        }
    }

    float* Cw = C;
    if constexpr (PANEL) Cw += (size_t)blockIdx.z * M * N;

#pragma unroll
    for (int i = 0; i < TM; ++i) {
        float4 f0, f1;
        if constexpr (PANEL) {
            f0.x = accB[i][0]; f0.y = accB[i][1]; f0.z = accB[i][2]; f0.w = accB[i][3];
            f1.x = accB[i][4]; f1.y = accB[i][5]; f1.z = accB[i][6]; f1.w = accB[i][7];
        } else {
            f0.x = accT[i][0]; f0.y = accT[i][1]; f0.z = accT[i][2]; f0.w = accT[i][3];
            f1.x = accT[i][4]; f1.y = accT[i][5]; f1.z = accT[i][6]; f1.w = accT[i][7];
        }
        const size_t rowoff = (size_t)(bm + ty * TM + i) * N + bn;
        *reinterpret_cast<float4*>(&Cw[rowoff + tx * 4]) = f0;
        *reinterpret_cast<float4*>(&Cw[rowoff + BN / 2 + tx * 4]) = f1;
    }
}

// Fold panel partials ascending: out = (((0+p0)+p1)+...)
template <int NP>
__global__ __launch_bounds__(256) void fold_panels(const float* __restrict__ parts,
                                                   float* __restrict__ out, size_t n) {
    const size_t n4 = n / 4;
    for (size_t i = blockIdx.x * 256ull + threadIdx.x; i < n4;
         i += (size_t)gridDim.x * 256) {
        float4 p = reinterpret_cast<const float4*>(parts)[i];
        float ax = 0.0f + p.x, ay = 0.0f + p.y, az = 0.0f + p.z, aw = 0.0f + p.w;
#pragma unroll
        for (int q = 1; q < NP; ++q) {
            const float4 r =
                reinterpret_cast<const float4*>(parts + (size_t)q * n)[i];
            ax += r.x; ay += r.y; az += r.z; aw += r.w;
        }
        float4 o; o.x = ax; o.y = ay; o.z = az; o.w = aw;
        reinterpret_cast<float4*>(out)[i] = o;
    }
}

// ---------------------------------------------------------------------------
// Softmax, np-literal math (R17-identical ops). FUSED2 folds the two s-panels
// ((0+p0)+p1) before beta*s — exactly the unfused op sequence.
// ---------------------------------------------------------------------------
template <bool FUSED2>
__global__ __launch_bounds__(256) void softmax_rows_np32(const float* __restrict__ P,
                                                         float* __restrict__ W,
                                                         const float* __restrict__ log_beta) {
    const int N = 4096;
    const float beta = expf(log_beta[0]);
    const size_t roff = (size_t)blockIdx.x * N;
    const int tid = threadIdx.x;

    float t[16];
    float m = -3.402823466e+38f;
#pragma unroll
    for (int i = 0; i < 16; ++i) {
        const size_t idx = roff + i * 256 + tid;
        float s;
        if constexpr (FUSED2) {
            s = (0.0f + P[idx]) + P[(size_t)2048 * 4096 + idx];
        } else {
            s = W[idx];
        }
        t[i] = beta * s;
        m = fmaxf(m, t[i]);
    }
#pragma unroll
    for (int off = 32; off; off >>= 1) m = fmaxf(m, __shfl_xor(m, off));

    __shared__ float red[4];
    if ((tid & 63) == 0) red[tid >> 6] = m;
    __syncthreads();
    m = fmaxf(fmaxf(red[0], red[1]), fmaxf(red[2], red[3]));

    float e[16];
    float sum = 0.0f;
#pragma unroll
    for (int i = 0; i < 16; ++i) {
        e[i] = expf(t[i] - m);
        sum += e[i];
    }
#pragma unroll
    for (int off = 32; off; off >>= 1) sum += __shfl_xor(sum, off);
    __syncthreads();
    if ((tid & 63) == 0) red[tid >> 6] = sum;
    __syncthreads();
    sum = red[0] + red[1] + red[2] + red[3];

#pragma unroll
    for (int i = 0; i < 16; ++i) W[roff + i * 256 + tid] = e[i] / sum;
}

__global__ __launch_bounds__(256) void sentinel(float* __restrict__ out, size_t n,
                                                float value) {
    for (size_t i = blockIdx.x * 256ull + threadIdx.x; i < n; i += (size_t)gridDim.x * 256)
        out[i] = (i == 0) ? value : 0.f;
}

// ---------------------------------------------------------------------------
// Orchestration. Base 72 MiB; fast path +64 MiB (zpart). Slow = R19 verbatim.
// ---------------------------------------------------------------------------
extern "C" void kernel_launch(void* const* d_in, const int* in_sizes, int n_in,
                              void* d_out, int out_size, void* d_ws, size_t ws_size,
                              hipStream_t stream) {
    const float* query    = (const float*)d_in[0];
    const float* patterns = (const float*)d_in[1];
    const float* W_q      = (const float*)d_in[2];
    const float* W_k      = (const float*)d_in[3];
    const float* W_v      = (const float*)d_in[4];
    const float* log_beta = (const float*)d_in[5];
    float* out = (float*)d_out;

    const int B = 2048, N = 4096, D = 1024;
    const dim3 blk(256);

    const size_t NEED_BASE = ((size_t)N * D * 2 + (size_t)B * D + (size_t)B * N) * 4;  // 72 MiB
    const size_t ZPART = (size_t)2 * B * N * 4;  // 64 MiB
    if (ws_size < NEED_BASE) {
        sentinel<<<dim3(2048), blk, 0, stream>>>(out, (size_t)B * D,
                                                 16.0f * (float)(9000000 + (ws_size >> 20)));
        return;
    }
    const bool fast = ws_size >= NEED_BASE + ZPART;

    char* ws = (char*)d_ws;
    float* k_ = (float*)ws; ws += (size_t)N * D * 4;  // 16 MiB
    float* v_ = (float*)ws; ws += (size_t)N * D * 4;  // 16 MiB
    float* qp = (float*)ws; ws += (size_t)B * D * 4;  //  8 MiB
    float* s  = (float*)ws; ws += (size_t)B * N * 4;  // 32 MiB
    float* zpart = (float*)ws;                        // 64 MiB (fast only)

    // ---- setup: k, v via 2-panel split (partials in dead s buffer) ----
    gemm_core<512, 128, 128, 32, 8, 8, true, true>
        <<<dim3(D / 128, N / 128, 2), blk, 0, stream>>>(patterns, W_k, s, N, D, D);
    fold_panels<2><<<dim3(2048), blk, 0, stream>>>(s, k_, (size_t)N * D);
    gemm_core<512, 128, 128, 32, 8, 8, true, true>
        <<<dim3(D / 128, N / 128, 2), blk, 0, stream>>>(patterns, W_v, s, N, D, D);
    fold_panels<2><<<dim3(2048), blk, 0, stream>>>(s, v_, (size_t)N * D);

    const float* zin = query;
    if (fast) {
        for (int t = 0; t < 31; ++t) {
            // qp: panels -> s, fold -> qp
            gemm_core<512, 64, 128, 32, 4, 8, true, true>
                <<<dim3(D / 128, B / 64, 2), blk, 0, stream>>>(zin, W_q, s, B, D, D);
            fold_panels<2><<<dim3(2048), blk, 0, stream>>>(s, qp, (size_t)B * D);
            // s-GEMM: 256x128 tile, 2-panel split -> zpart
            gemm_big<512, true>
                <<<dim3(N / 128, B / 256, 2), blk, 0, stream>>>(qp, k_, zpart, B, N, D);
            // softmax with fused 2-panel fold: zpart -> s
            softmax_rows_np32<true><<<dim3(B), blk, 0, stream>>>(zpart, s, log_beta);
            // z-GEMM: 256x128 tile, 8-panel split -> zpart, fold -> out
            gemm_big<512, false>
                <<<dim3(D / 128, B / 256, 8), blk, 0, stream>>>(s, v_, zpart, B, D, N);
            fold_panels<8><<<dim3(2048), blk, 0, stream>>>(zpart, out, (size_t)B * D);
            zin = out;
        }
    } else {
        for (int t = 0; t < 31; ++t) {
            gemm_core<512, 64, 128, 32, 4, 8, true, true>
                <<<dim3(D / 128, B / 64, 2), blk, 0, stream>>>(zin, W_q, s, B, D, D);
            fold_panels<2><<<dim3(2048), blk, 0, stream>>>(s, qp, (size_t)B * D);
            gemm_core<512, 128, 128, 32, 8, 8, true, false>
                <<<dim3(N / 128, B / 128), blk, 0, stream>>>(qp, k_, s, B, N, D);
            softmax_rows_np32<false><<<dim3(B), blk, 0, stream>>>(nullptr, s, log_beta);
            gemm_core<512, 128, 128, 32, 8, 8, false, false>
                <<<dim3(D / 128, B / 128), blk, 0, stream>>>(s, v_, out, B, D, N);
            zin = out;
        }
    }
}

// Round 25
// 14575.957 us; speedup vs baseline: 1.1198x; 1.0921x over previous
//
#include <hip/hip_runtime.h>
#include <hip/hip_bf16.h>

// ---------------------------------------------------------------------------
// FINAL (R25 = R19, best measured: 14,629 us, absmax 0.0078125).
// ARITHMETIC (locked since R17 — the golden's exact semantics):
//   f32 pipeline; every GEMM element = ascending-k fmaf chain per KC=512
//   panel (BLIS-Zen4/Eigen-class), panel partials folded ascending
//   ((0+p0)+p1...); np-literal softmax. Any reassociation flips attractor
//   basins (whole-v-row errors) — 17 rounds of evidence.
// SCHEDULE: 128x128x32 tiles, 8x8/thread, split-K over panels + ascending
//   fold kernels, fused qp-fold into s-GEMM A-staging, fused s-panel fold
//   into softmax. Plateau analysis (R20-R24, five null/negative levers):
//   this is the LDS-pipe/barrier ceiling of the 2-barrier plain-HIP f32
//   class (~53% of the 157TF vector peak; VALUBusy ~60%).
// ---------------------------------------------------------------------------

template <int KC, int BM, int BN, int BK, int TM, int TN, bool BT, bool PANEL,
          bool FOLDA>
__global__ __launch_bounds__(256, 2) void gemm_core(const float* __restrict__ A,
                                                    const float* __restrict__ A2,
                                                    const float* __restrict__ B,
                                                    float* __restrict__ C,
                                                    int M, int N, int K) {
    constexpr int TX = BN / TN;
    constexpr int TY = BM / TM;
    static_assert(TX * TY == 256, "thread count");
    static_assert(KC % BK == 0, "KC multiple of BK");
    static_assert(TN == 8 && TX * 4 == BN / 2, "column-chunk mapping");
    static_assert(TM % 4 == 0, "float4 fragments");

    __shared__ float As[BK][BM + 4];
    __shared__ float Bs[BK][BN + 4];

    const int tid = threadIdx.x;
    const int tx = tid % TX;
    const int ty = tid / TX;
    const int bm = blockIdx.y * BM;
    const int bn = blockIdx.x * BN;

    const int kbeg = PANEL ? blockIdx.z * KC : 0;
    const int kend = PANEL ? kbeg + KC : K;

    float accB[TM][TN];
    float accT[TM][TN];
#pragma unroll
    for (int i = 0; i < TM; ++i)
#pragma unroll
        for (int j = 0; j < TN; ++j) { accB[i][j] = 0.0f; accT[i][j] = 0.0f; }

    for (int k0 = kbeg; k0 < kend; k0 += BK) {
        // ---- stage A tile [BM][BK] -> As[BK][BM] (transposed; optional fused
        //      ascending fold of two partial arrays) ----
        constexpr int APT = (BM * BK / 4) / 256;
        static_assert(APT >= 1, "A staging");
#pragma unroll
        for (int i = 0; i < APT; ++i) {
            const int idx = tid + i * 256;
            const int row = idx / (BK / 4);
            const int kq = idx % (BK / 4);
            const size_t off = (size_t)(bm + row) * K + k0 + kq * 4;
            float4 f = *reinterpret_cast<const float4*>(&A[off]);
            if constexpr (FOLDA) {
                const float4 g = *reinterpret_cast<const float4*>(&A2[off]);
                f.x += g.x; f.y += g.y; f.z += g.z; f.w += g.w;
            }
            As[kq * 4 + 0][row] = f.x;
            As[kq * 4 + 1][row] = f.y;
            As[kq * 4 + 2][row] = f.z;
            As[kq * 4 + 3][row] = f.w;
        }
        // ---- stage B tile ----
        constexpr int BPT = (BN * BK / 4) / 256;
        static_assert(BPT >= 1, "B staging");
        if (BT) {
#pragma unroll
            for (int i = 0; i < BPT; ++i) {
                const int idx = tid + i * 256;
                const int col = idx / (BK / 4);
                const int kq = idx % (BK / 4);
                const float4 f = *reinterpret_cast<const float4*>(
                    &B[(size_t)(bn + col) * K + k0 + kq * 4]);
                Bs[kq * 4 + 0][col] = f.x;
                Bs[kq * 4 + 1][col] = f.y;
                Bs[kq * 4 + 2][col] = f.z;
                Bs[kq * 4 + 3][col] = f.w;
            }
        } else {
#pragma unroll
            for (int i = 0; i < BPT; ++i) {
                const int idx = tid + i * 256;
                const int kk = idx / (BN / 4);
                const int nq = idx % (BN / 4);
                const float4 f = *reinterpret_cast<const float4*>(
                    &B[(size_t)(k0 + kk) * N + bn + nq * 4]);
                *reinterpret_cast<float4*>(&Bs[kk][nq * 4]) = f;
            }
        }
        __syncthreads();

        // ---- strict ascending-k fmaf chain per output element ----
#pragma unroll
        for (int kk = 0; kk < BK; ++kk) {
            float a[TM], b[TN];
#pragma unroll
            for (int i = 0; i < TM; i += 4) {
                const float4 f = *reinterpret_cast<const float4*>(&As[kk][ty * TM + i]);
                a[i + 0] = f.x; a[i + 1] = f.y; a[i + 2] = f.z; a[i + 3] = f.w;
            }
            {   // column chunks tx*4 and BN/2 + tx*4 (2-way banks, free)
                const float4 f0 = *reinterpret_cast<const float4*>(&Bs[kk][tx * 4]);
                const float4 f1 =
                    *reinterpret_cast<const float4*>(&Bs[kk][BN / 2 + tx * 4]);
                b[0] = f0.x; b[1] = f0.y; b[2] = f0.z; b[3] = f0.w;
                b[4] = f1.x; b[5] = f1.y; b[6] = f1.z; b[7] = f1.w;
            }
#pragma unroll
            for (int i = 0; i < TM; ++i)
#pragma unroll
                for (int j = 0; j < TN; ++j)
                    accB[i][j] = __builtin_fmaf(a[i], b[j], accB[i][j]);
        }
        __syncthreads();

        if constexpr (!PANEL) {
            if (((k0 + BK) % KC) == 0) {
#pragma unroll
                for (int i = 0; i < TM; ++i)
#pragma unroll
                    for (int j = 0; j < TN; ++j) {
                        accT[i][j] += accB[i][j];
                        accB[i][j] = 0.0f;
                    }
            }
        }
    }

    float* Cw = C;
    if constexpr (PANEL) {
        Cw += (size_t)blockIdx.z * M * N;
    } else {
#pragma unroll
        for (int i = 0; i < TM; ++i)
#pragma unroll
            for (int j = 0; j < TN; ++j) accT[i][j] += accB[i][j];
    }

#pragma unroll
    for (int i = 0; i < TM; ++i) {
        float4 f0, f1;
        if constexpr (PANEL) {
            f0.x = accB[i][0]; f0.y = accB[i][1]; f0.z = accB[i][2]; f0.w = accB[i][3];
            f1.x = accB[i][4]; f1.y = accB[i][5]; f1.z = accB[i][6]; f1.w = accB[i][7];
        } else {
            f0.x = accT[i][0]; f0.y = accT[i][1]; f0.z = accT[i][2]; f0.w = accT[i][3];
            f1.x = accT[i][4]; f1.y = accT[i][5]; f1.z = accT[i][6]; f1.w = accT[i][7];
        }
        const size_t rowoff = (size_t)(bm + ty * TM + i) * N + bn;
        *reinterpret_cast<float4*>(&Cw[rowoff + tx * 4]) = f0;
        *reinterpret_cast<float4*>(&Cw[rowoff + BN / 2 + tx * 4]) = f1;
    }
}

// Fold panel partials ascending: out = (((0+p0)+p1)+...)  (bitwise = accT fold)
template <int NP>
__global__ __launch_bounds__(256) void fold_panels(const float* __restrict__ parts,
                                                   float* __restrict__ out, size_t n) {
    const size_t n4 = n / 4;
    for (size_t i = blockIdx.x * 256ull + threadIdx.x; i < n4;
         i += (size_t)gridDim.x * 256) {
        float4 p = reinterpret_cast<const float4*>(parts)[i];
        float ax = 0.0f + p.x, ay = 0.0f + p.y, az = 0.0f + p.z, aw = 0.0f + p.w;
#pragma unroll
        for (int q = 1; q < NP; ++q) {
            const float4 r =
                reinterpret_cast<const float4*>(parts + (size_t)q * n)[i];
            ax += r.x; ay += r.y; az += r.z; aw += r.w;
        }
        float4 o; o.x = ax; o.y = ay; o.z = az; o.w = aw;
        reinterpret_cast<float4*>(out)[i] = o;
    }
}

// ---------------------------------------------------------------------------
// Softmax, np-literal math (R17-identical ops). FUSED2 folds the two s-panels
// ((0+p0)+p1) before beta*s — exactly the unfused op sequence.
// ---------------------------------------------------------------------------
template <bool FUSED2>
__global__ __launch_bounds__(256) void softmax_rows_np32(const float* __restrict__ P,
                                                         float* __restrict__ W,
                                                         const float* __restrict__ log_beta) {
    const int N = 4096;
    const float beta = expf(log_beta[0]);
    const size_t roff = (size_t)blockIdx.x * N;
    const int tid = threadIdx.x;

    float t[16];
    float m = -3.402823466e+38f;
#pragma unroll
    for (int i = 0; i < 16; ++i) {
        const size_t idx = roff + i * 256 + tid;
        float s;
        if constexpr (FUSED2) {
            s = (0.0f + P[idx]) + P[(size_t)2048 * 4096 + idx];
        } else {
            s = W[idx];
        }
        t[i] = beta * s;
        m = fmaxf(m, t[i]);
    }
#pragma unroll
    for (int off = 32; off; off >>= 1) m = fmaxf(m, __shfl_xor(m, off));

    __shared__ float red[4];
    if ((tid & 63) == 0) red[tid >> 6] = m;
    __syncthreads();
    m = fmaxf(fmaxf(red[0], red[1]), fmaxf(red[2], red[3]));

    float e[16];
    float sum = 0.0f;
#pragma unroll
    for (int i = 0; i < 16; ++i) {
        e[i] = expf(t[i] - m);
        sum += e[i];
    }
#pragma unroll
    for (int off = 32; off; off >>= 1) sum += __shfl_xor(sum, off);
    __syncthreads();
    if ((tid & 63) == 0) red[tid >> 6] = sum;
    __syncthreads();
    sum = red[0] + red[1] + red[2] + red[3];

#pragma unroll
    for (int i = 0; i < 16; ++i) W[roff + i * 256 + tid] = e[i] / sum;
}

__global__ __launch_bounds__(256) void sentinel(float* __restrict__ out, size_t n,
                                                float value) {
    for (size_t i = blockIdx.x * 256ull + threadIdx.x; i < n; i += (size_t)gridDim.x * 256)
        out[i] = (i == 0) ? value : 0.f;
}

// ---------------------------------------------------------------------------
// Orchestration. Base scratch 72 MiB; fast path needs +64 MiB (zpart).
// ---------------------------------------------------------------------------
extern "C" void kernel_launch(void* const* d_in, const int* in_sizes, int n_in,
                              void* d_out, int out_size, void* d_ws, size_t ws_size,
                              hipStream_t stream) {
    const float* query    = (const float*)d_in[0];
    const float* patterns = (const float*)d_in[1];
    const float* W_q      = (const float*)d_in[2];
    const float* W_k      = (const float*)d_in[3];
    const float* W_v      = (const float*)d_in[4];
    const float* log_beta = (const float*)d_in[5];
    float* out = (float*)d_out;

    const int B = 2048, N = 4096, D = 1024;
    const dim3 blk(256);

    const size_t NEED_BASE = ((size_t)N * D * 2 + (size_t)B * D + (size_t)B * N) * 4;  // 72 MiB
    const size_t ZPART = (size_t)2 * B * N * 4;  // 64 MiB
    if (ws_size < NEED_BASE) {
        sentinel<<<dim3(2048), blk, 0, stream>>>(out, (size_t)B * D,
                                                 16.0f * (float)(9000000 + (ws_size >> 20)));
        return;
    }
    const bool fast = ws_size >= NEED_BASE + ZPART;

    char* ws = (char*)d_ws;
    float* k_ = (float*)ws; ws += (size_t)N * D * 4;  // 16 MiB
    float* v_ = (float*)ws; ws += (size_t)N * D * 4;  // 16 MiB
    float* qp = (float*)ws; ws += (size_t)B * D * 4;  //  8 MiB
    float* s  = (float*)ws; ws += (size_t)B * N * 4;  // 32 MiB
    float* zpart = (float*)ws;                        // 64 MiB (fast only)

    // ---- setup: k, v via 2-panel split (partials in dead s buffer) ----
    gemm_core<512, 128, 128, 32, 8, 8, true, true, false>
        <<<dim3(D / 128, N / 128, 2), blk, 0, stream>>>(patterns, nullptr, W_k, s, N, D, D);
    fold_panels<2><<<dim3(2048), blk, 0, stream>>>(s, k_, (size_t)N * D);
    gemm_core<512, 128, 128, 32, 8, 8, true, true, false>
        <<<dim3(D / 128, N / 128, 2), blk, 0, stream>>>(patterns, nullptr, W_v, s, N, D, D);
    fold_panels<2><<<dim3(2048), blk, 0, stream>>>(s, v_, (size_t)N * D);

    const float* zin = query;
    if (fast) {
        for (int t = 0; t < 31; ++t) {
            // qp panels -> s buffer (2 x 8 MiB)
            gemm_core<512, 64, 128, 32, 4, 8, true, true, false>
                <<<dim3(D / 128, B / 64, 2), blk, 0, stream>>>(zin, nullptr, W_q, s, B, D, D);
            // s-GEMM: A = qp0+qp1 (fused fold), 2-panel split-K -> zpart
            gemm_core<512, 128, 128, 32, 8, 8, true, true, true>
                <<<dim3(N / 128, B / 128, 2), blk, 0, stream>>>(s, s + (size_t)B * D, k_,
                                                                zpart, B, N, D);
            // softmax with fused 2-panel fold: reads zpart, writes w into s
            softmax_rows_np32<true><<<dim3(B), blk, 0, stream>>>(zpart, s, log_beta);
            // z-GEMM: 8-panel split -> zpart, fold -> out
            gemm_core<512, 128, 128, 32, 8, 8, false, true, false>
                <<<dim3(D / 128, B / 128, 8), blk, 0, stream>>>(s, nullptr, v_, zpart, B, D, N);
            fold_panels<8><<<dim3(2048), blk, 0, stream>>>(zpart, out, (size_t)B * D);
            zin = out;
        }
    } else {
        for (int t = 0; t < 31; ++t) {
            gemm_core<512, 64, 128, 32, 4, 8, true, true, false>
                <<<dim3(D / 128, B / 64, 2), blk, 0, stream>>>(zin, nullptr, W_q, s, B, D, D);
            fold_panels<2><<<dim3(2048), blk, 0, stream>>>(s, qp, (size_t)B * D);
            gemm_core<512, 128, 128, 32, 8, 8, true, false, false>
                <<<dim3(N / 128, B / 128), blk, 0, stream>>>(qp, nullptr, k_, s, B, N, D);
            softmax_rows_np32<false><<<dim3(B), blk, 0, stream>>>(nullptr, s, log_beta);
            gemm_core<512, 128, 128, 32, 8, 8, false, false, false>
                <<<dim3(D / 128, B / 128), blk, 0, stream>>>(s, nullptr, v_, out, B, D, N);
            zin = out;
        }
    }
}